// Round 16
// baseline (2063.271 us; speedup 1.0000x reference)
//
#include <hip/hip_runtime.h>
#include <math.h>

// Conv1D(k=2,F=64,relu) -> LSTM1(H=100, relu cell, seq) -> LSTM2 (last) ->
// Dense(3) -> softmax.  B=128, T=2048, T'=2047.
//
// Round-21 = r20 (1844.6us best) with ONE change: block 512 -> 448 threads
// (7 waves, was 8).
//  Model update from r20's null: VALUBusy 56% is CU-level -> issue is only
//  ~300cy of the 2160cy step; ~85% is barrier rendezvous + LDS turnaround +
//  dependency latency.  The one untried lever: rendezvous WIDTH.  Producer's
//  dedicated conv wave (nearly idle, pure barrier skew) folds into wave 6's
//  48 idle lanes (lanes 400-447: filters f=lane-400, +2nd filter 48+f for
//  f<16); consumer's companion wave (barrier-count filler) is deleted.
//  One fewer wave at every one of 2047 barriers in both roles.
//  __launch_bounds__(448,1): 1 block/CU, 2 waves/SIMD, 256-reg budget.
//  Everything else r20-identical: layer-split pipeline, (p,g2,kh) mapping,
//  DPP psum2/xswap2, packed f16 weights, 4-slot ring, counted-vmcnt
//  step_barrier (lgkmcnt-only).

typedef _Float16 h2 __attribute__((ext_vector_type(2)));

#define TT 2048
#define TP 2047
#define HH 100
#define G4 400
#define FF 64
#define NB 128

#define X1R 176              // producer operand row halves (2x88)
#define CBQ 104              // consumer row halves (100 + pad4)
#define NPW (400 * 88)       // producer packed h2
#define NCW (400 * 100)      // consumer packed h2
#define CHK 64
#define NCHUNK 32
#define RINGC 4
#define CHUNK_DW (CHK * 50)  // 3200 dwords per ring slot

// ws layout in 4B units
#define WS_FLAGS (NPW + NCW)       // pflag[128], aflag[128]
#define WS_RING  (WS_FLAGS + 256)  // 128 * RINGC * CHUNK_DW dwords

#define FD2(w, xs, acc) acc = __builtin_amdgcn_fdot2(w, xs, acc, false)
#define B2(f) __builtin_bit_cast(h2, f)

// DPP quad_perm: 0xB1 = xor-1, 0x4E = xor-2 (proven r6-r20)
static __device__ __forceinline__ float psum2(float z) {
    int p = __builtin_amdgcn_update_dpp(0, __builtin_bit_cast(int, z),
                                        0xB1, 0xF, 0xF, true);
    return z + __builtin_bit_cast(float, p);
}
static __device__ __forceinline__ float xswap2(float z) {
    int p = __builtin_amdgcn_update_dpp(0, __builtin_bit_cast(int, z),
                                        0x4E, 0xF, 0xF, true);
    return __builtin_bit_cast(float, p);
}
static __device__ __forceinline__ float sig(float z) {
    return 1.0f / (1.0f + __expf(-z));
}
// per-step barrier: order LDS (lgkmcnt) but DO NOT drain vmcnt -- ring
// stores stay in flight across steps (drained once per chunk).
static __device__ __forceinline__ void step_barrier() {
    __builtin_amdgcn_sched_barrier(0);
    asm volatile("s_waitcnt lgkmcnt(0)" ::: "memory");
    __builtin_amdgcn_sched_barrier(0);
    __builtin_amdgcn_s_barrier();
    __builtin_amdgcn_sched_barrier(0);
}

// ---------------- prep kernel: pack weights f16 in per-thread order --------
// thread rt = (p<<2)|(g2<<1)|kh ; gates cL=(2*g2)*100+p, cH=cL+100.
// pack: float4 j = (a_{2j}, b_{2j}, a_{2j+1}, b_{2j+1})
__global__ void prep_weights(const float* __restrict__ w1, const float* __restrict__ u1,
                             const float* __restrict__ w2, const float* __restrict__ u2,
                             h2* __restrict__ ws)
{
    const int idx = blockIdx.x * 256 + threadIdx.x;
    if (idx >= NPW + NCW) return;
    float lo = 0.f, hi = 0.f;
    if (idx < NPW) {
        // producer: 88 h2/thread = 22 float4
        const int rt = idx / 88, r = idx % 88;
        const int qq = (r >> 2) * 2 + ((r & 3) >> 1);   // h2 pair index 0..43
        const int gs = r & 1;                           // 0 -> cL, 1 -> cH
        const int p = rt >> 2, g2 = (rt >> 1) & 1, kh = rt & 1;
        const int col = (2 * g2 + gs) * HH + p;
        const int E0 = 2 * qq;                          // in-half elem
#pragma unroll
        for (int e = 0; e < 2; ++e) {
            const int E = E0 + e;
            float v = 0.f;
            if (E < 82) {
                const int k = kh * 82 + E;              // orig combined-K index
                v = (k < FF) ? w1[k * G4 + col] : u1[(k - FF) * G4 + col];
            }
            if (e == 0) lo = v; else hi = v;
        }
    } else {
        // consumer: 100 h2/thread = 25 float4
        const int i2 = idx - NPW;
        const int rt = i2 / 100, r = i2 % 100;
        const int qq = (r >> 2) * 2 + ((r & 3) >> 1);   // 0..49
        const int gs = r & 1;
        const int p = rt >> 2, g2 = (rt >> 1) & 1, kh = rt & 1;
        const int col = (2 * g2 + gs) * HH + p;
        const int k0 = 2 * qq;
        const float* M = kh ? u2 : w2;
        lo = M[k0 * G4 + col];
        hi = M[(k0 + 1) * G4 + col];
    }
    ws[idx] = h2{(_Float16)lo, (_Float16)hi};
}

// ---------------- main kernel ----------------------------------------------
__global__ __launch_bounds__(448, 1)
void fused_lstm_kernel(const float* __restrict__ s,       // [B,T]
                       const float* __restrict__ conv_w,  // [2,1,F]
                       const float* __restrict__ conv_b,  // [F]
                       const float* __restrict__ b1,
                       const float* __restrict__ b2,
                       const float* __restrict__ dw, const float* __restrict__ db,
                       h2* __restrict__ wpk,              // weights + flags + ring
                       float* __restrict__ out)           // [B,3]
{
    const int tid  = threadIdx.x;
    const int bb   = blockIdx.x;
    const int b    = bb & (NB - 1);
    const bool prod = bb < NB;

    int* pflag = (int*)(wpk + WS_FLAGS) + b;
    int* aflag = (int*)(wpk + WS_FLAGS) + 128 + b;
    unsigned* ring = (unsigned*)(wpk + WS_RING) + (size_t)b * (RINGC * CHUNK_DW);

    __shared__ float s_buf[TT];                        // producer only
    __shared__ __align__(16) _Float16 X1[2 * X1R];     // producer operand ring
    __shared__ __align__(16) _Float16 CB[CHK * CBQ];   // consumer staged chunk
    __shared__ __align__(16) _Float16 HR[2 * CBQ];     // consumer h2 ring

    if (prod) {
        for (int i = tid; i < TT; i += 448) s_buf[i] = s[(size_t)b * TT + i];
        if (tid < X1R) ((unsigned*)X1)[tid] = 0u;      // both slots zero (pads stay 0)
    } else {
        if (tid < CBQ) ((unsigned*)HR)[tid] = 0u;      // 2*104 halves = 104 dwords
        if (tid < CHK * 2)                             // CB pad dwords [50,52)/row
            ((unsigned*)CB)[(tid >> 1) * 52 + 50 + (tid & 1)] = 0u;
    }
    __syncthreads();                                   // (A)

    if (prod) {
        // ============ PRODUCER block: LSTM1 (lanes<400) + conv (400-447) ====
        const int rt = tid;
        const int active = rt < 400;
        const int lrt = active ? rt : 0;
        const int p  = lrt >> 2;
        const int g2 = (lrt >> 1) & 1;
        const int kh = lrt & 1;
        const int cL = (2 * g2) * HH + p;

        h2 wa[44], wb[44];
        {
            const float4* w4 = (const float4*)(wpk + (size_t)lrt * 88);
#pragma unroll
            for (int j = 0; j < 22; ++j) {
                const float4 v = w4[j];
                wa[2*j]   = B2(v.x); wb[2*j]   = B2(v.y);
                wa[2*j+1] = B2(v.z); wb[2*j+1] = B2(v.w);
            }
        }
        const float bL = b1[cL], bH = b1[cL + HH];
        const int hoff = (p < 18) ? (64 + p) : (p + 70);  // h1[p] slot offset

        // conv duty for lanes 400-447: filter f1 = rt-400 (0..47); lanes with
        // f1<16 also own filter 48+f1.
        const int f1 = rt - 400;
        float cv0 = 0.f, cv1 = 0.f, cb0 = 0.f, cv0b = 0.f, cv1b = 0.f, cb0b = 0.f;
        if (!active) {
            cv0 = conv_w[f1]; cv1 = conv_w[FF + f1]; cb0 = conv_b[f1];
            if (f1 < 16) { cv0b = conv_w[48 + f1]; cv1b = conv_w[FF + 48 + f1]; cb0b = conv_b[48 + f1]; }
        }
        if (!active) {                                 // x(0) into slot 0
            X1[f1] = (_Float16)fmaxf(fmaf(s_buf[0], cv0, fmaf(s_buf[1], cv1, cb0)), 0.f);
            if (f1 < 16)
                X1[48 + f1] = (_Float16)fmaxf(fmaf(s_buf[0], cv0b, fmaf(s_buf[1], cv1b, cb0b)), 0.f);
        }
        __syncthreads();                               // (B)

        float c = 0.0f;
        for (int t = 0; t < TP; ++t) {
            if ((t & 63) == 0) {                       // chunk start: ring credit
                const int k = t >> 6;
                if (tid == 0 && k >= RINGC) {
                    int g = 0;
                    while (__hip_atomic_load(aflag, __ATOMIC_ACQUIRE,
                                             __HIP_MEMORY_SCOPE_AGENT) < k - (RINGC - 1)
                           && g < 50000000) { ++g; __builtin_amdgcn_s_sleep(8); }
                }
                __syncthreads();
            }
            if (active) {
                _Float16* cur = X1 + (t & 1) * X1R;
                _Float16* nx1 = X1 + ((t & 1) ^ 1) * X1R;
                float za0 = 0.f, za1 = 0.f, zb0 = 0.f, zb1 = 0.f;
                const float4* vb = (const float4*)(cur + kh * 88);
#pragma unroll
                for (int r2 = 0; r2 < 11; ++r2) {
                    const float4 v = vb[r2];
                    FD2(wa[4*r2+0], B2(v.x), za0); FD2(wb[4*r2+0], B2(v.x), zb0);
                    FD2(wa[4*r2+1], B2(v.y), za1); FD2(wb[4*r2+1], B2(v.y), zb1);
                    FD2(wa[4*r2+2], B2(v.z), za0); FD2(wb[4*r2+2], B2(v.z), zb0);
                    FD2(wa[4*r2+3], B2(v.w), za1); FD2(wb[4*r2+3], B2(v.w), zb1);
                }
                const float zaS = psum2(za0 + za1) + bL;
                const float zbS = psum2(zb0 + zb1) + bH;
                const float oa = xswap2(zaS), ob = xswap2(zbS);
                const float zi = g2 ? oa  : zaS;
                const float zf = g2 ? ob  : zbS;
                const float zg = g2 ? zaS : oa;
                const float zo = g2 ? zbS : ob;
                c = fmaf(sig(zf), c, sig(zi) * fmaxf(zg, 0.f));
                const float h = sig(zo) * fmaxf(c, 0.f);
                if ((rt & 3) == 0) {
                    const _Float16 hq = (_Float16)h;
                    nx1[hoff] = hq;                    // h1 for LSTM1(t+1)
                    const unsigned hb = (unsigned)__builtin_bit_cast(unsigned short, hq);
                    const unsigned prt =
                        (unsigned)__builtin_amdgcn_ds_swizzle((int)hb, 0x101F) & 0xFFFFu;
                    if (!(p & 1))
                        __hip_atomic_store(ring + ((t >> 6) & 3) * CHUNK_DW
                                                + (t & 63) * 50 + (p >> 1),
                                           hb | (prt << 16), __ATOMIC_RELAXED,
                                           __HIP_MEMORY_SCOPE_AGENT);
                }
                if (((t & 63) == 63) || (t == TP - 1))
                    asm volatile("s_waitcnt vmcnt(0)" ::: "memory");
            } else if (t + 1 < TP) {                   // conv lanes: x(t+1)
                _Float16* nx1 = X1 + ((t & 1) ^ 1) * X1R;
                nx1[f1] = (_Float16)fmaxf(
                    fmaf(s_buf[t + 1], cv0, fmaf(s_buf[t + 2], cv1, cb0)), 0.f);
                if (f1 < 16)
                    nx1[48 + f1] = (_Float16)fmaxf(
                        fmaf(s_buf[t + 1], cv0b, fmaf(s_buf[t + 2], cv1b, cb0b)), 0.f);
            }
            step_barrier();                            // (C) one per step (no vm drain)
            if (tid == 0 && (((t & 63) == 63) || (t == TP - 1)))
                __hip_atomic_fetch_add(pflag, 1, __ATOMIC_RELEASE,
                                       __HIP_MEMORY_SCOPE_AGENT);
        }
    } else {
        // ================= CONSUMER block: LSTM2 + dense + softmax ==========
        const int rt = tid;
        const int active = rt < 400;
        const int lrt = active ? rt : 0;
        const int p  = lrt >> 2;
        const int g2 = (lrt >> 1) & 1;
        const int kh = lrt & 1;
        const int cL = (2 * g2) * HH + p;

        h2 wa[50], wb[50];
        {
            const float4* w4 = (const float4*)(wpk + NPW + (size_t)lrt * 100);
#pragma unroll
            for (int j = 0; j < 25; ++j) {
                const float4 v = w4[j];
                wa[2*j]   = B2(v.x); wb[2*j]   = B2(v.y);
                wa[2*j+1] = B2(v.z); wb[2*j+1] = B2(v.w);
            }
        }
        const float bL = b2[cL], bH = b2[cL + HH];
        __syncthreads();                               // (B)

        float c = 0.0f;
        for (int k = 0; k < NCHUNK; ++k) {
            if (tid == 0) {                            // wait for producer chunk k
                int g = 0;
                while (__hip_atomic_load(pflag, __ATOMIC_ACQUIRE,
                                         __HIP_MEMORY_SCOPE_AGENT) < k + 1
                       && g < 50000000) { ++g; __builtin_amdgcn_s_sleep(8); }
            }
            __syncthreads();                           // chunk ready
            const int csz = (TP - (k << 6) < CHK) ? (TP - (k << 6)) : CHK;
            unsigned* gsrc = ring + (k & 3) * CHUNK_DW;
            for (int d = tid; d < csz * 50; d += 448)
                ((unsigned*)CB)[(d / 50) * 52 + (d % 50)] =
                    __hip_atomic_load(gsrc + d, __ATOMIC_RELAXED,
                                      __HIP_MEMORY_SCOPE_AGENT);
            __syncthreads();                           // staged
            if (tid == 0)
                __hip_atomic_fetch_add(aflag, 1, __ATOMIC_RELAXED,
                                       __HIP_MEMORY_SCOPE_AGENT);
            for (int lt = 0; lt < csz; ++lt) {
                const int t = (k << 6) + lt;
                if (active) {
                    const _Float16* base = kh ? (HR + (t & 1) * CBQ)
                                              : (CB + lt * CBQ);
                    float za0 = 0.f, za1 = 0.f, zb0 = 0.f, zb1 = 0.f;
                    const float4* vb = (const float4*)base;
#pragma unroll
                    for (int r2 = 0; r2 < 12; ++r2) {
                        const float4 v = vb[r2];
                        FD2(wa[4*r2+0], B2(v.x), za0); FD2(wb[4*r2+0], B2(v.x), zb0);
                        FD2(wa[4*r2+1], B2(v.y), za1); FD2(wb[4*r2+1], B2(v.y), zb1);
                        FD2(wa[4*r2+2], B2(v.z), za0); FD2(wb[4*r2+2], B2(v.z), zb0);
                        FD2(wa[4*r2+3], B2(v.w), za1); FD2(wb[4*r2+3], B2(v.w), zb1);
                    }
                    {                                  // tail halves 96..99
                        const float2 tv = *(const float2*)(base + 96);
                        FD2(wa[48], B2(tv.x), za0); FD2(wb[48], B2(tv.x), zb0);
                        FD2(wa[49], B2(tv.y), za1); FD2(wb[49], B2(tv.y), zb1);
                    }
                    const float zaS = psum2(za0 + za1) + bL;
                    const float zbS = psum2(zb0 + zb1) + bH;
                    const float oa = xswap2(zaS), ob = xswap2(zbS);
                    const float zi = g2 ? oa  : zaS;
                    const float zf = g2 ? ob  : zbS;
                    const float zg = g2 ? zaS : oa;
                    const float zo = g2 ? zbS : ob;
                    c = fmaf(sig(zf), c, sig(zi) * fmaxf(zg, 0.f));
                    const float h = sig(zo) * fmaxf(c, 0.f);
                    if ((rt & 3) == 0)
                        HR[((t & 1) ^ 1) * CBQ + p] = (_Float16)h;
                }
                step_barrier();                        // (C)
            }
        }

        // final h2(t=2046) was written into slot ((2046&1)^1)=1
        if (rt == 0) {
            float l[3];
#pragma unroll
            for (int a = 0; a < 3; ++a) {
                float acc = db[a];
                for (int j = 0; j < HH; ++j)
                    acc = fmaf((float)HR[CBQ + j], dw[j * 3 + a], acc);
                l[a] = acc;
            }
            const float m = fmaxf(l[0], fmaxf(l[1], l[2]));
            const float e0 = __expf(l[0] - m), e1 = __expf(l[1] - m), e2 = __expf(l[2] - m);
            const float inv = 1.0f / (e0 + e1 + e2);
            out[b * 3 + 0] = e0 * inv;
            out[b * 3 + 1] = e1 * inv;
            out[b * 3 + 2] = e2 * inv;
        }
    }
}

// ---------------- launch ----------------------------------------------------
extern "C" void kernel_launch(void* const* d_in, const int* in_sizes, int n_in,
                              void* d_out, int out_size, void* d_ws, size_t ws_size,
                              hipStream_t stream) {
    const float* s      = (const float*)d_in[0];
    const float* conv_w = (const float*)d_in[1];
    const float* conv_b = (const float*)d_in[2];
    const float* w1     = (const float*)d_in[3];
    const float* u1     = (const float*)d_in[4];
    const float* b1     = (const float*)d_in[5];
    const float* w2     = (const float*)d_in[6];
    const float* u2     = (const float*)d_in[7];
    const float* b2     = (const float*)d_in[8];
    const float* dw     = (const float*)d_in[9];
    const float* db     = (const float*)d_in[10];

    h2* ws = (h2*)d_ws;
    hipMemsetAsync((void*)((int*)(ws + WS_FLAGS)), 0, 256 * sizeof(int), stream);
    const int nh2 = NPW + NCW;
    prep_weights<<<(nh2 + 255) / 256, 256, 0, stream>>>(w1, u1, w2, u2, ws);
    fused_lstm_kernel<<<256, 448, 0, stream>>>(
        s, conv_w, conv_b, b1, b2, dw, db, ws, (float*)d_out);
}